// Round 11
// baseline (127.377 us; speedup 1.0000x reference)
//
#include <hip/hip_runtime.h>
#include <math.h>

// Morphological dilation, k=4x4, TF SAME padding (pad top/left=1, bottom/right=2).
// x: (8, 512, 512, 32) fp32 NHWC;  w: (4, 4, 32) fp32;  out: same as x.
// out[b,y,x,c] = max_{i,j} x[b, y+i-1, x+j-1, c] + w[i,j,c]  (OOB -> -inf)
//
// Lessons R1-R9: allocator keeps this kernel in the 64-VGPR tier no matter
// what; every variant must truly fit ~56 regs or it spills (R2/R9) or drops
// MLP (R5/R6/R7). R4 (scalar, T=16 unrolled strip) = 97.4 us, limited by
// dependent add/max chains (VALUBusy 40%) on top of HBM.
// R11 (=R10 fixed): channel-pair per thread, dwordx2 loads + packed-f16
// arithmetic (v_cvt_pkrtz -> v_pk_add_f16/v_pk_max_f16). Halves arith ops
// AND fits the 64-tier. f16 error ~0.004 << 0.109 threshold.
// Note: cvt_pkrtz returns __fp16-based vectors, so h2 must be __fp16.

constexpr int H = 512;
constexpr int W = 512;
constexpr int C = 32;
constexpr int T = 16;  // output rows per thread (y-strip)

typedef __fp16 h2  __attribute__((ext_vector_type(2)));
typedef float  f2n __attribute__((ext_vector_type(2)));

__device__ __forceinline__ h2 hmax2(h2 a, h2 b) {
    return __builtin_elementwise_max(a, b);   // v_pk_max_f16
}

template<bool EDGE>
__device__ __forceinline__ void dil_body(const float* __restrict__ xb,
                                         const h2 wv[16],
                                         h2 acc[T],
                                         const int y0, const int xp) {
    h2 NEG;
    NEG.x = (__fp16)(-INFINITY);
    NEG.y = (__fp16)(-INFINITY);
#pragma unroll
    for (int r = 0; r < T + 3; ++r) {
        int yy = y0 - 1 + r;
        bool yok = true;
        if (EDGE) {
            yok = ((unsigned)yy < (unsigned)H);
            yy = min(max(yy, 0), H - 1);          // safe clamped address
        }
        const float* rowp = xb + (size_t)yy * (W * C);

        h2 px[4];
#pragma unroll
        for (int j = 0; j < 4; ++j) {
            int xx = xp + j - 1;
            if (EDGE) {
                bool ok = yok & ((unsigned)xx < (unsigned)W);
                xx = min(max(xx, 0), W - 1);
                f2n v = *reinterpret_cast<const f2n*>(rowp + (size_t)xx * C);
                h2 p = __builtin_amdgcn_cvt_pkrtz(v.x, v.y);
                px[j] = ok ? p : NEG;
            } else {
                f2n v = *reinterpret_cast<const f2n*>(rowp + (size_t)xx * C);
                px[j] = __builtin_amdgcn_cvt_pkrtz(v.x, v.y);
            }
        }

#pragma unroll
        for (int i = 0; i < 4; ++i) {
            const int t = r - i;            // unroll-constant: static acc index
            if (t < 0 || t >= T) continue;  // folded at compile time
            h2 v = hmax2(hmax2(px[0] + wv[i * 4 + 0], px[1] + wv[i * 4 + 1]),
                         hmax2(px[2] + wv[i * 4 + 2], px[3] + wv[i * 4 + 3]));
            acc[t] = hmax2(acc[t], v);
        }
    }
}

__global__ void dil2d_kernel(const float* __restrict__ xin,
                             const float* __restrict__ wt,
                             float* __restrict__ out) {
    // thread -> (channel-pair, x): lanes walk c then x
    // -> 64 lanes x 8 B = 512 B contiguous per wave load instruction.
    const int c2 = (threadIdx.x & 15) * 2;       // channel base 0,2,...,30
    const int xl = threadIdx.x >> 4;             // 0..15
    const int xp = blockIdx.x * 16 + xl;         // 0..511
    const int y0 = blockIdx.y * T;               // strip start row
    const int b  = blockIdx.z;

    // 4x4 weight taps for our channel pair, pre-converted to packed f16
    h2 wv[16];
#pragma unroll
    for (int k = 0; k < 16; ++k) {
        f2n t = *reinterpret_cast<const f2n*>(wt + k * C + c2);
        wv[k] = __builtin_amdgcn_cvt_pkrtz(t.x, t.y);
    }

    h2 acc[T];
#pragma unroll
    for (int t = 0; t < T; ++t) {
        acc[t].x = (__fp16)(-INFINITY);
        acc[t].y = (__fp16)(-INFINITY);
    }

    const float* xb = xin + (size_t)b * H * W * C + c2;

    // wave-uniform edge classification: interior blocks take the
    // zero-bounds-logic straight-line path.
    const bool yedge = (blockIdx.y == 0) || (blockIdx.y == gridDim.y - 1);
    const bool xedge = (blockIdx.x == 0) || (blockIdx.x == gridDim.x - 1);

    if (yedge | xedge) dil_body<true >(xb, wv, acc, y0, xp);
    else               dil_body<false>(xb, wv, acc, y0, xp);

    float* ob = out + (((size_t)b * H + y0) * W + xp) * C + c2;
#pragma unroll
    for (int t = 0; t < T; ++t) {
        f2n o;
        o.x = (float)acc[t].x;
        o.y = (float)acc[t].y;
        __builtin_nontemporal_store(
            o, reinterpret_cast<f2n*>(ob + (size_t)t * W * C));
    }
}

extern "C" void kernel_launch(void* const* d_in, const int* in_sizes, int n_in,
                              void* d_out, int out_size, void* d_ws, size_t ws_size,
                              hipStream_t stream) {
    const float* x = (const float*)d_in[0];
    const float* w = (const float*)d_in[1];
    float* o = (float*)d_out;

    dim3 block(256);
    dim3 grid(W / 16,   // 32: x tiles (16 x-positions per block)
              H / T,    // 32: y strips
              8);       // batch
    dil2d_kernel<<<grid, block, 0, stream>>>(x, w, o);
}

// Round 12
// 97.281 us; speedup vs baseline: 1.3094x; 1.3094x over previous
//
#include <hip/hip_runtime.h>
#include <math.h>

// Morphological dilation, k=4x4, TF SAME padding (pad top/left=1, bottom/right=2).
// x: (8, 512, 512, 32) fp32 NHWC;  w: (4, 4, 32) fp32;  out: same as x.
// out[b,y,x,c] = max_{i,j} x[b, y+i-1, x+j-1, c] + w[i,j,c]  (OOB -> -inf)
//
// FINAL (= R4, the measured optimum of 8 structural variants R3-R11):
// scalar-per-channel thread, T=16 fully-unrolled y-strip, NT stores.
// 97.4 us = 5.95 TB/s logical (580 MB incl. 1.19x y-halo) = 95% of the
// measured D2D copy ceiling (6.29 TB/s). Variants tried and refuted:
//   T=8 (128 us, more halo) | T=32 (101 us, loads sunk, VGPR=48)
//   ring acc (103-107 us, runtime loop kills load pipelining, VGPR=32)
//   float2 (112 us, 64-VGPR tier spill) | packed f16 (127 us, VALU wasn't
//   the limit - VALUBusy 18% yet slower).
// Allocator pins 256-thread blocks at the 64-VGPR tier; only this variant
// both fits it (~48 regs) and keeps the fully-unrolled load pipeline.

constexpr int H = 512;
constexpr int W = 512;
constexpr int C = 32;
constexpr int T = 16;  // output rows per thread (y-strip)

template<bool EDGE>
__device__ __forceinline__ void dil_body(const float* __restrict__ xb,
                                         const float wv[16],
                                         float acc[T],
                                         const int y0, const int xp) {
    const float NI = -INFINITY;
#pragma unroll
    for (int r = 0; r < T + 3; ++r) {
        int yy = y0 - 1 + r;
        bool yok = true;
        if (EDGE) {
            yok = ((unsigned)yy < (unsigned)H);
            yy = min(max(yy, 0), H - 1);          // safe clamped address
        }
        const float* rowp = xb + (size_t)yy * (W * C);

        float px[4];
#pragma unroll
        for (int j = 0; j < 4; ++j) {
            int xx = xp + j - 1;
            if (EDGE) {
                bool ok = yok & ((unsigned)xx < (unsigned)W);
                xx = min(max(xx, 0), W - 1);
                float v = rowp[(size_t)xx * C];
                px[j] = ok ? v : NI;
            } else {
                px[j] = rowp[(size_t)xx * C];
            }
        }

#pragma unroll
        for (int i = 0; i < 4; ++i) {
            const int t = r - i;            // unroll-constant: static acc index
            if (t < 0 || t >= T) continue;  // folded at compile time
            float v = fmaxf(fmaxf(px[0] + wv[i * 4 + 0], px[1] + wv[i * 4 + 1]),
                            fmaxf(px[2] + wv[i * 4 + 2], px[3] + wv[i * 4 + 3]));
            acc[t] = fmaxf(acc[t], v);
        }
    }
}

__global__ __launch_bounds__(256)
void dil2d_kernel(const float* __restrict__ xin,
                  const float* __restrict__ wt,
                  float* __restrict__ out) {
    // thread -> (channel, x): lanes walk c then x -> 256 B contiguous per wave load
    const int c  = threadIdx.x & (C - 1);        // 0..31
    const int xl = threadIdx.x >> 5;             // 0..7
    const int xp = blockIdx.x * 8 + xl;          // 0..511
    const int y0 = blockIdx.y * T;               // strip start row
    const int b  = blockIdx.z;

    // hoist the 4x4 weight taps for our channel into registers (16 VGPRs)
    float wv[16];
#pragma unroll
    for (int k = 0; k < 16; ++k)
        wv[k] = wt[k * C + c];

    float acc[T];
#pragma unroll
    for (int t = 0; t < T; ++t) acc[t] = -INFINITY;

    const float* xb = xin + (size_t)b * H * W * C + c;

    // wave-uniform edge classification: 58/64 x-tiles x 30/32 y-strips take
    // the zero-bounds-logic straight-line path.
    const bool yedge = (blockIdx.y == 0) || (blockIdx.y == gridDim.y - 1);
    const bool xedge = (blockIdx.x == 0) || (blockIdx.x == gridDim.x - 1);

    if (yedge | xedge) dil_body<true >(xb, wv, acc, y0, xp);
    else               dil_body<false>(xb, wv, acc, y0, xp);

    float* ob = out + (((size_t)b * H + y0) * W + xp) * C + c;
#pragma unroll
    for (int t = 0; t < T; ++t)
        __builtin_nontemporal_store(acc[t], ob + (size_t)t * W * C);
}

extern "C" void kernel_launch(void* const* d_in, const int* in_sizes, int n_in,
                              void* d_out, int out_size, void* d_ws, size_t ws_size,
                              hipStream_t stream) {
    const float* x = (const float*)d_in[0];
    const float* w = (const float*)d_in[1];
    float* o = (float*)d_out;

    dim3 block(256);
    dim3 grid(W / 8,    // 64: x tiles (8 x-positions per block)
              H / T,    // 32: y strips
              8);       // batch
    dil2d_kernel<<<grid, block, 0, stream>>>(x, w, o);
}